// Round 5
// baseline (323.758 us; speedup 1.0000x reference)
//
#include <hip/hip_runtime.h>

// SIZE=65536 nodes, MAX_EDGES=16777216.
// out[i] = bias[i] + sum over edges e with dst[e]==i of x[src[e]]*w[e].
//
// R1: global fp32 atomics ~20.6 G/s, ~32B HBM write each -> LDS histograms.
// R2/R3: LDS hist, RANGES x private ws copies, tree reduce.
// R4: RANGES=2 via 128KB dynamic LDS halved traffic but only -22% time ->
//     latency-bound (~1300 cyc/wave-iter, no counter saturated). Guarded
//     gathers had the vmcnt wait INSIDE each branch -> serialized.
// R5: fully branch-free inner loop (cndmask'd gather index, ds_add of 0.0
//     for masked lanes) + hand 2-deep software pipeline: E-loads 2 ahead,
//     gathers 1 ahead, ~14 loads in flight per wave.

#define NNODES  65536
#define NEDGES  16777216
#define RANGES  2
#define BINS    (NNODES / RANGES)   // 32768 bins -> 128 KB dynamic LDS
#define THREADS 1024
#define NCOPIES 128                 // private output copies in ws (32 MB)
#define GROUPS  16
#define CPG     (NCOPIES / GROUPS)

struct EQ { int4 sa, sb, da, db; float4 wa, wb; };

__device__ __forceinline__ EQ load_eq(const int4* __restrict__ s4,
                                      const int4* __restrict__ d4,
                                      const float4* __restrict__ w4, int g) {
    EQ e;
    e.sa = s4[2 * g];     e.sb = s4[2 * g + 1];
    e.da = d4[2 * g];     e.db = d4[2 * g + 1];
    e.wa = w4[2 * g];     e.wb = w4[2 * g + 1];
    return e;
}

struct Frag { unsigned bin[8]; float xv[8]; float wv[8]; };

// Compute bins, issue all 8 gathers branch-free. Masked lanes gather x[0]
// (single coalesced extra sector). Multiply deferred to ds_pass so the
// vmcnt wait lands once, after everything is in flight.
__device__ __forceinline__ void issue_gather(const float* __restrict__ x,
                                             const EQ& e, int lo, Frag& f) {
    const int s[8] = { e.sa.x, e.sa.y, e.sa.z, e.sa.w,
                       e.sb.x, e.sb.y, e.sb.z, e.sb.w };
    const int d[8] = { e.da.x, e.da.y, e.da.z, e.da.w,
                       e.db.x, e.db.y, e.db.z, e.db.w };
    const float wv[8] = { e.wa.x, e.wa.y, e.wa.z, e.wa.w,
                          e.wb.x, e.wb.y, e.wb.z, e.wb.w };
    #pragma unroll
    for (int k = 0; k < 8; ++k) {
        unsigned bin = (unsigned)(d[k] - lo);
        unsigned idx = (bin < (unsigned)BINS) ? (unsigned)s[k] : 0u;
        f.bin[k] = bin;
        f.xv[k]  = x[idx];        // unconditional gather
        f.wv[k]  = wv[k];
    }
}

// Branch-free LDS accumulate: masked lanes add 0.0f to a folded bin.
__device__ __forceinline__ void ds_pass(float* h, const Frag& f) {
    #pragma unroll
    for (int k = 0; k < 8; ++k) {
        float val = (f.bin[k] < (unsigned)BINS) ? f.xv[k] * f.wv[k] : 0.0f;
        atomicAdd(&h[f.bin[k] & (BINS - 1)], val);
    }
}

// ---------------- Stage 1: LDS histograms ----------------
__global__ __launch_bounds__(THREADS, 4) void hist_kernel(
    const float* __restrict__ x,
    const float* __restrict__ w,
    const int*   __restrict__ src,
    const int*   __restrict__ dst,
    float*       __restrict__ ws,
    int B)
{
    extern __shared__ float h[];   // BINS floats = 128 KB

    const int b  = blockIdx.x;
    const int r  = b & (RANGES - 1);
    const int c  = b >> 1;
    const int lo = r * BINS;

    for (int i = threadIdx.x; i < BINS; i += THREADS) h[i] = 0.0f;
    __syncthreads();

    const int4*   src4 = (const int4*)src;
    const int4*   dst4 = (const int4*)dst;
    const float4* wgt4 = (const float4*)w;

    const int n8      = NEDGES / 8;
    const int gstride = B * THREADS;
    const int iters   = n8 / gstride;
    int g = c * THREADS + (int)threadIdx.x;

    if (iters * gstride == n8 && iters >= 3) {
        // -------- pipelined fast path --------
        EQ e0 = load_eq(src4, dst4, wgt4, g);
        EQ e1 = load_eq(src4, dst4, wgt4, g + gstride);
        Frag f0;
        issue_gather(x, e0, lo, f0);           // G[0]

        for (int i = 0; i + 1 < iters; ++i) {
            int gl = (i + 2 < iters) ? (g + 2 * gstride) : g;  // E[i+2]
            EQ e2 = load_eq(src4, dst4, wgt4, gl);
            Frag f1;
            issue_gather(x, e1, lo, f1);       // G[i+1] (E[i+1] landed)
            ds_pass(h, f0);                    // consume G[i]
            f0 = f1; e1 = e2; g += gstride;
        }
        ds_pass(h, f0);
    } else {
        // -------- generic fallback --------
        for (int gg = g; gg < n8; gg += gstride) {
            EQ e = load_eq(src4, dst4, wgt4, gg);
            Frag f;
            issue_gather(x, e, lo, f);
            ds_pass(h, f);
        }
    }
    __syncthreads();

    // Vectorized flush of private bins (non-atomic).
    float4* outc4 = (float4*)(ws + (size_t)c * NNODES + lo);
    const float4* h4 = (const float4*)h;
    for (int i = threadIdx.x; i < BINS / 4; i += THREADS) outc4[i] = h4[i];
}

// ---------------- Stage 2a: tree reduce 128 -> 16 (in-place) ----------------
__global__ __launch_bounds__(256) void reduceA_kernel(float* __restrict__ ws)
{
    const int NB = NNODES / (256 * 4);          // 64 slice-blocks per group
    int g  = blockIdx.x / NB;
    int jb = blockIdx.x % NB;
    int i4 = jb * 256 + (int)threadIdx.x;

    float4* w4 = (float4*)ws;
    const int stride4 = NNODES / 4;

    float4 acc = w4[(size_t)(g * CPG) * stride4 + i4];
    #pragma unroll
    for (int cc = 1; cc < CPG; ++cc) {
        float4 t = w4[(size_t)(g * CPG + cc) * stride4 + i4];
        acc.x += t.x; acc.y += t.y; acc.z += t.z; acc.w += t.w;
    }
    w4[(size_t)(g * CPG) * stride4 + i4] = acc;
}

// ---------------- Stage 2b: 16 partials + bias -> out ----------------
__global__ __launch_bounds__(256) void reduceB_kernel(
    const float* __restrict__ ws,
    const float* __restrict__ bias,
    float*       __restrict__ out)
{
    int i4 = blockIdx.x * 256 + (int)threadIdx.x;
    const float4* w4 = (const float4*)ws;
    const int stride4 = NNODES / 4;

    float4 acc = ((const float4*)bias)[i4];
    #pragma unroll
    for (int g = 0; g < GROUPS; ++g) {
        float4 t = w4[(size_t)(g * CPG) * stride4 + i4];
        acc.x += t.x; acc.y += t.y; acc.z += t.z; acc.w += t.w;
    }
    ((float4*)out)[i4] = acc;
}

// ---------------- Generic fallback reduce (B != NCOPIES) ----------------
__global__ __launch_bounds__(256) void reduce_generic_kernel(
    const float* __restrict__ ws,
    const float* __restrict__ bias,
    float*       __restrict__ out,
    int B)
{
    int i = blockIdx.x * 256 + (int)threadIdx.x;
    float acc = bias[i];
    for (int cc = 0; cc < B; ++cc) acc += ws[(size_t)cc * NNODES + i];
    out[i] = acc;
}

// ---------------- Fallback: global atomics (tiny ws) ----------------
__global__ __launch_bounds__(256) void init_out_kernel(
    const float* __restrict__ bias, float* __restrict__ out)
{
    int i = blockIdx.x * blockDim.x + threadIdx.x;
    if (i < NNODES) out[i] = bias[i];
}

__global__ __launch_bounds__(256) void edge_atomic_kernel(
    const float* __restrict__ x, const float* __restrict__ w,
    const int* __restrict__ src, const int* __restrict__ dst,
    float* __restrict__ out)
{
    const int n4 = NEDGES / 4;
    int tid = blockIdx.x * blockDim.x + threadIdx.x;
    int stride = gridDim.x * blockDim.x;
    for (int i = tid; i < n4; i += stride) {
        int4 s = ((const int4*)src)[i];
        int4 d = ((const int4*)dst)[i];
        float4 ww = ((const float4*)w)[i];
        atomicAdd(&out[d.x], x[s.x] * ww.x);
        atomicAdd(&out[d.y], x[s.y] * ww.y);
        atomicAdd(&out[d.z], x[s.z] * ww.z);
        atomicAdd(&out[d.w], x[s.w] * ww.w);
    }
}

extern "C" void kernel_launch(void* const* d_in, const int* in_sizes, int n_in,
                              void* d_out, int out_size, void* d_ws, size_t ws_size,
                              hipStream_t stream) {
    const float* x    = (const float*)d_in[0];
    const float* w    = (const float*)d_in[1];
    const float* bias = (const float*)d_in[2];
    const int*   src  = (const int*)d_in[3];
    const int*   dst  = (const int*)d_in[4];
    float* out = (float*)d_out;
    float* ws  = (float*)d_ws;

    size_t copies = ws_size / ((size_t)NNODES * sizeof(float));
    int B = (int)(copies < NCOPIES ? copies : NCOPIES);

    if (B >= 1) {
        hist_kernel<<<B * RANGES, THREADS, BINS * sizeof(float), stream>>>(
            x, w, src, dst, ws, B);
        if (B == NCOPIES) {
            reduceA_kernel<<<GROUPS * (NNODES / 1024), 256, 0, stream>>>(ws);
            reduceB_kernel<<<NNODES / 1024, 256, 0, stream>>>(ws, bias, out);
        } else {
            reduce_generic_kernel<<<NNODES / 256, 256, 0, stream>>>(ws, bias, out, B);
        }
    } else {
        init_out_kernel<<<NNODES / 256, 256, 0, stream>>>(bias, out);
        edge_atomic_kernel<<<4096, 256, 0, stream>>>(x, w, src, dst, out);
    }
}

// Round 6
// 274.959 us; speedup vs baseline: 1.1775x; 1.1775x over previous
//
#include <hip/hip_runtime.h>

// SIZE=65536 nodes, MAX_EDGES=16777216.
// out[i] = bias[i] + sum over edges e with dst[e]==i of x[src[e]]*w[e].
//
// R1: global fp32 atomics ~20.6 G/s -> LDS histograms + private ws copies.
// R4: RANGES=2 (128KB dynamic LDS), guarded gathers: 140us. VGPR=20 ->
//     compiler sank each gather to its use: per-edge serialized chain.
// R5: branch-free (unconditional gather + ds_add of 0) REGRESSED to 190us:
//     doubled active-lane work on TA/LDS-atomic pipes (~1-2cyc per active
//     divergent lane, invisible in rocprof). Guards are load-bearing.
// R6: R4 structure + bare guarded gathers (no mul inside guard -> no wait
//     between the 8 loads) + sched_barrier(0) to defeat the register-
//     minimizing sink. Target: batch the 8 L2 round-trips into one.

#define NNODES  65536
#define NEDGES  16777216
#define RANGES  2
#define BINS    (NNODES / RANGES)   // 32768 bins -> 128 KB dynamic LDS
#define THREADS 1024
#define NCOPIES 128                 // private output copies in ws (32 MB)
#define GROUPS  16
#define CPG     (NCOPIES / GROUPS)

// ---------------- Stage 1: LDS histograms ----------------
// Block b: range r = b&1, chunk c = b>>1. Scans chunk c of the edge list,
// accumulates dst in [r*BINS,(r+1)*BINS) into a 128KB LDS histogram, then
// flushes (non-atomic) to private copy ws[c]. 8 edges per thread-iteration.
__global__ __launch_bounds__(THREADS, 4) void hist_kernel(
    const float* __restrict__ x,
    const float* __restrict__ w,
    const int*   __restrict__ src,
    const int*   __restrict__ dst,
    float*       __restrict__ ws,
    int B)
{
    extern __shared__ float h[];   // BINS floats = 128 KB

    const int b  = blockIdx.x;
    const int r  = b & (RANGES - 1);
    const int c  = b >> 1;
    const int lo = r * BINS;

    for (int i = threadIdx.x; i < BINS; i += THREADS) h[i] = 0.0f;
    __syncthreads();

    const int4*   src4 = (const int4*)src;
    const int4*   dst4 = (const int4*)dst;
    const float4* wgt4 = (const float4*)w;

    const int n8 = NEDGES / 8;
    for (int g = c * THREADS + (int)threadIdx.x; g < n8; g += B * THREADS) {
        int4   sa = src4[2 * g], sb = src4[2 * g + 1];
        int4   da = dst4[2 * g], db = dst4[2 * g + 1];
        float4 wa = wgt4[2 * g], wb = wgt4[2 * g + 1];

        int      s[8]  = { sa.x, sa.y, sa.z, sa.w, sb.x, sb.y, sb.z, sb.w };
        unsigned bin[8] = {
            (unsigned)(da.x - lo), (unsigned)(da.y - lo),
            (unsigned)(da.z - lo), (unsigned)(da.w - lo),
            (unsigned)(db.x - lo), (unsigned)(db.y - lo),
            (unsigned)(db.z - lo), (unsigned)(db.w - lo) };
        float    wv[8] = { wa.x, wa.y, wa.z, wa.w, wb.x, wb.y, wb.z, wb.w };

        // Pass 1: bare guarded gathers. No use inside the branch -> the 8
        // exec-masked loads issue back-to-back with NO waitcnt between
        // them; the wait lands once, at first use in pass 2.
        float xv[8];
        #pragma unroll
        for (int k = 0; k < 8; ++k) {
            xv[k] = 0.0f;
            if (bin[k] < (unsigned)BINS) xv[k] = x[s[k]];
        }

        // Forbid the scheduler from sinking the gathers into pass 2
        // (R4's VGPR=20 showed it serialized per-edge to save registers).
        __builtin_amdgcn_sched_barrier(0);

        // Pass 2: guarded LDS atomics (masked lanes are ~free on the LDS
        // atomic pipe -- R5 proved unguarded doubles that pipe's work).
        #pragma unroll
        for (int k = 0; k < 8; ++k) {
            if (bin[k] < (unsigned)BINS) atomicAdd(&h[bin[k]], xv[k] * wv[k]);
        }
    }
    __syncthreads();

    // Vectorized flush of private bins (non-atomic).
    float4* outc4 = (float4*)(ws + (size_t)c * NNODES + lo);
    const float4* h4 = (const float4*)h;
    for (int i = threadIdx.x; i < BINS / 4; i += THREADS) outc4[i] = h4[i];
}

// ---------------- Stage 2a: tree reduce 128 -> 16 (in-place) ----------------
__global__ __launch_bounds__(256) void reduceA_kernel(float* __restrict__ ws)
{
    const int NB = NNODES / (256 * 4);          // 64 slice-blocks per group
    int g  = blockIdx.x / NB;
    int jb = blockIdx.x % NB;
    int i4 = jb * 256 + (int)threadIdx.x;

    float4* w4 = (float4*)ws;
    const int stride4 = NNODES / 4;

    float4 acc = w4[(size_t)(g * CPG) * stride4 + i4];
    #pragma unroll
    for (int cc = 1; cc < CPG; ++cc) {
        float4 t = w4[(size_t)(g * CPG + cc) * stride4 + i4];
        acc.x += t.x; acc.y += t.y; acc.z += t.z; acc.w += t.w;
    }
    w4[(size_t)(g * CPG) * stride4 + i4] = acc;
}

// ---------------- Stage 2b: 16 partials + bias -> out ----------------
__global__ __launch_bounds__(256) void reduceB_kernel(
    const float* __restrict__ ws,
    const float* __restrict__ bias,
    float*       __restrict__ out)
{
    int i4 = blockIdx.x * 256 + (int)threadIdx.x;
    const float4* w4 = (const float4*)ws;
    const int stride4 = NNODES / 4;

    float4 acc = ((const float4*)bias)[i4];
    #pragma unroll
    for (int g = 0; g < GROUPS; ++g) {
        float4 t = w4[(size_t)(g * CPG) * stride4 + i4];
        acc.x += t.x; acc.y += t.y; acc.z += t.z; acc.w += t.w;
    }
    ((float4*)out)[i4] = acc;
}

// ---------------- Generic fallback reduce (B != NCOPIES) ----------------
__global__ __launch_bounds__(256) void reduce_generic_kernel(
    const float* __restrict__ ws,
    const float* __restrict__ bias,
    float*       __restrict__ out,
    int B)
{
    int i = blockIdx.x * 256 + (int)threadIdx.x;
    float acc = bias[i];
    for (int cc = 0; cc < B; ++cc) acc += ws[(size_t)cc * NNODES + i];
    out[i] = acc;
}

// ---------------- Fallback: global atomics (tiny ws) ----------------
__global__ __launch_bounds__(256) void init_out_kernel(
    const float* __restrict__ bias, float* __restrict__ out)
{
    int i = blockIdx.x * blockDim.x + threadIdx.x;
    if (i < NNODES) out[i] = bias[i];
}

__global__ __launch_bounds__(256) void edge_atomic_kernel(
    const float* __restrict__ x, const float* __restrict__ w,
    const int* __restrict__ src, const int* __restrict__ dst,
    float* __restrict__ out)
{
    const int n4 = NEDGES / 4;
    int tid = blockIdx.x * blockDim.x + threadIdx.x;
    int stride = gridDim.x * blockDim.x;
    for (int i = tid; i < n4; i += stride) {
        int4 s = ((const int4*)src)[i];
        int4 d = ((const int4*)dst)[i];
        float4 ww = ((const float4*)w)[i];
        atomicAdd(&out[d.x], x[s.x] * ww.x);
        atomicAdd(&out[d.y], x[s.y] * ww.y);
        atomicAdd(&out[d.z], x[s.z] * ww.z);
        atomicAdd(&out[d.w], x[s.w] * ww.w);
    }
}

extern "C" void kernel_launch(void* const* d_in, const int* in_sizes, int n_in,
                              void* d_out, int out_size, void* d_ws, size_t ws_size,
                              hipStream_t stream) {
    const float* x    = (const float*)d_in[0];
    const float* w    = (const float*)d_in[1];
    const float* bias = (const float*)d_in[2];
    const int*   src  = (const int*)d_in[3];
    const int*   dst  = (const int*)d_in[4];
    float* out = (float*)d_out;
    float* ws  = (float*)d_ws;

    size_t copies = ws_size / ((size_t)NNODES * sizeof(float));
    int B = (int)(copies < NCOPIES ? copies : NCOPIES);

    if (B >= 1) {
        hist_kernel<<<B * RANGES, THREADS, BINS * sizeof(float), stream>>>(
            x, w, src, dst, ws, B);
        if (B == NCOPIES) {
            reduceA_kernel<<<GROUPS * (NNODES / 1024), 256, 0, stream>>>(ws);
            reduceB_kernel<<<NNODES / 1024, 256, 0, stream>>>(ws, bias, out);
        } else {
            reduce_generic_kernel<<<NNODES / 256, 256, 0, stream>>>(ws, bias, out, B);
        }
    } else {
        init_out_kernel<<<NNODES / 256, 256, 0, stream>>>(bias, out);
        edge_atomic_kernel<<<4096, 256, 0, stream>>>(x, w, src, dst, out);
    }
}